// Round 4
// baseline (601.687 us; speedup 1.0000x reference)
//
#include <hip/hip_runtime.h>

// SVDQuantLinear: out[m,n] = x[m,:] . (w_q[n,:]*w_scale[n]) + bias[n] + lora
// Fold rank-32 LoRA into dequantized W (fp32, one bf16 round) -> one bf16 GEMM.
// R3: 256x256/BK=32 ring-4, counted vmcnt, lgkm(0)+sched_barrier+setprio
//     cluster, XCD swizzle -> conflicts 0, MfmaUtil 48%, gemm 258us. BEST.
// R4 FAILED: coarse 2-phase split -> 298us (extra barriers + double drains).
// R5 FAILED: removing lgkm(0)+sched_barrier -> 268us (compiler interleave is
//     NOT better than the tight drained cluster). R3 schedule is kept as-is.
// R6 (this round): kill the x-cast kernel. A-staging now reg-stages directly
//     from fp32 x: float4 loads issued 1 K-tile early -> v_cvt_pk_bf16_f32
//     (RNE, identical numerics to f2bf) -> ds_write_b128 into the SAME LDS
//     image (same pre-swizzled global col, linear lane*16 dest). B keeps
//     global_load_lds from folded Wbf. Removes: one kernel launch + graph
//     dependency + 192MB HBM (Xbf write+read). prep is now fold-only (32MB).
//     Gate ladder recounted for new issue mix: steady vmcnt(8), tail 2/0;
//     compiler's auto-wait on x-regs (vmcnt(2)/tile) enforces B(t+1) arrival.

#define M_DIM 8192   // B*S
#define N_DIM 4096   // D_OUT
#define K_DIM 4096   // D_IN
#define R_DIM 32

#define BM 256
#define BN 256
#define BK 32                 // 64 B per row in LDS
#define NT (K_DIM / BK)       // 128 k-tiles
#define NSLOT 4               // LDS ring: 4 * (16KB A + 16KB B) = 128 KiB

typedef short bf16x8 __attribute__((ext_vector_type(8)));
typedef float f32x4 __attribute__((ext_vector_type(4)));
typedef unsigned short u16x8 __attribute__((ext_vector_type(8)));

#define GLOBAL_AS __attribute__((address_space(1)))
#define LDS_AS __attribute__((address_space(3)))

__device__ __forceinline__ unsigned short f2bf(float f) {
  union { float f; unsigned u; } v;
  v.f = f;
  unsigned u = v.u;
  u += 0x7fffu + ((u >> 16) & 1u);  // RNE (finite inputs)
  return (unsigned short)(u >> 16);
}

// pack 8 fp32 -> 8 bf16 (RNE) via v_cvt_pk_bf16_f32: D.lo=bf16(S0), D.hi=bf16(S1)
__device__ __forceinline__ int4 cvt8(float4 lo, float4 hi) {
  int4 w;
  asm("v_cvt_pk_bf16_f32 %0, %1, %2" : "=v"(w.x) : "v"(lo.x), "v"(lo.y));
  asm("v_cvt_pk_bf16_f32 %0, %1, %2" : "=v"(w.y) : "v"(lo.z), "v"(lo.w));
  asm("v_cvt_pk_bf16_f32 %0, %1, %2" : "=v"(w.z) : "v"(hi.x), "v"(hi.y));
  asm("v_cvt_pk_bf16_f32 %0, %1, %2" : "=v"(w.w) : "v"(hi.z), "v"(hi.w));
  return w;
}

// ---------------- fold W_eff = wq*scale + lora_B*diag(S)*lora_A -> bf16 ----
// 2048 blocks: block = 4 o-rows x 2048 i-cols; thread = 8 i-cols x 4 o-rows.
__global__ void fold_kernel(const int* __restrict__ wq,
                            const float* __restrict__ wscale,
                            const float* __restrict__ lA,
                            const float* __restrict__ lS,
                            const float* __restrict__ lB,
                            unsigned short* __restrict__ Wbf) {
  __shared__ float bs[4][32];
  const int tid = threadIdx.x;
  const int o0 = (int)(blockIdx.x >> 1) * 4;
  const int i0 = (int)(blockIdx.x & 1) * 2048 + tid * 8;

  if (tid < 128) {
    int o = tid >> 5, r = tid & 31;
    bs[o][r] = lB[(size_t)(o0 + o) * R_DIM + r] * lS[r];
  }
  __syncthreads();

  float acc[4][8];
#pragma unroll
  for (int o = 0; o < 4; ++o)
#pragma unroll
    for (int j = 0; j < 8; ++j) acc[o][j] = 0.f;

  for (int r = 0; r < R_DIM; ++r) {
    float4 a0 = *(const float4*)(lA + (size_t)r * K_DIM + i0);
    float4 a1 = *(const float4*)(lA + (size_t)r * K_DIM + i0 + 4);
    float av[8] = {a0.x, a0.y, a0.z, a0.w, a1.x, a1.y, a1.z, a1.w};
#pragma unroll
    for (int o = 0; o < 4; ++o) {
      float b = bs[o][r];
#pragma unroll
      for (int j = 0; j < 8; ++j) acc[o][j] += b * av[j];
    }
  }

#pragma unroll
  for (int o = 0; o < 4; ++o) {
    float sc = wscale[o0 + o];
    const int* qp = wq + (size_t)(o0 + o) * K_DIM + i0;
    int4 q0 = *(const int4*)qp;
    int4 q1 = *(const int4*)(qp + 4);
    int qv[8] = {q0.x, q0.y, q0.z, q0.w, q1.x, q1.y, q1.z, q1.w};
    u16x8 ov;
#pragma unroll
    for (int j = 0; j < 8; ++j) ov[j] = f2bf(acc[o][j] + (float)qv[j] * sc);
    *(u16x8*)(Wbf + (size_t)(o0 + o) * K_DIM + i0) = ov;
  }
}

// ---------------- main GEMM: C = cvt(x) * Wbf^T + bias ---------------------
// 256x256 tile, BK=32, 512 thr = 8 waves (2M x 4N), wave = 128x64 output =
// 8x4 frags of 16x16x32 MFMA. 4-slot LDS ring; counted vmcnt gates (T4).
// A path: x fp32 -> regs (issued 1 tile early) -> cvt_pk bf16 -> ds_write,
//   same LDS image as the old global_load_lds (pre-swizzled global col gsl,
//   linear lane*16B dest). B path: global_load_lds from Wbf (unchanged).
// LDS: 16B line (row, sl) holds k-group g = sl ^ ((row>>1)&3) (rule #21).
__global__ __launch_bounds__(512, 2) void gemm_bias_kernel(
    const float* __restrict__ X,            // [M, K] fp32
    const unsigned short* __restrict__ B,   // [N, K] bf16 bits (folded W)
    const float* __restrict__ bias,         // [N]
    float* __restrict__ C) {                // [M, N]
  __shared__ __align__(16) unsigned short sA[NSLOT][BM * BK];  // 4 x 16 KiB
  __shared__ __align__(16) unsigned short sB[NSLOT][BN * BK];  // 4 x 16 KiB

  const int tid = threadIdx.x;
  const int lane = tid & 63;
  const int wv = tid >> 6;      // 0..7
  const int wm = wv >> 2;       // 0..1
  const int wn = wv & 3;        // 0..3

  // T1: bijective XCD swizzle (grid = 512 = 8*64). XCD x owns 2 B-panels.
  const int bid = (int)blockIdx.x;
  const int s = ((bid & 7) << 6) + (bid >> 3);
  const int bn_ = s >> 5;       // 0..15
  const int bm_ = s & 31;       // 0..31
  const size_t m0 = (size_t)bm_ * BM;
  const size_t n0 = (size_t)bn_ * BN;

  // ---- staging geometry: lane l -> local row l>>2, 16B slot l&3,
  // global k-group (l&3)^((l>>3)&3); LDS dest linear (base + lane*16B).
  const int lrow = lane >> 2;                                  // 0..15
  const int gsl = (((lane & 3) ^ ((lane >> 3) & 3))) * 8;      // k elems
  const int r0 = (wv * 2) * 16 + lrow;                         // chunk c=0 row
  const float* xr0 = X + (m0 + r0) * (size_t)K_DIM + gsl;      // A fp32 src
  const float* xr1 = xr0 + 16 * (size_t)K_DIM;
  const unsigned short* gB0 = B + (n0 + r0) * (size_t)K_DIM + gsl;
  const unsigned short* gB1 = gB0 + 16 * (size_t)K_DIM;
  const int ch0 = (wv * 2 + 0) * 512;   // LDS chunk bases (shorts, 1KB each)
  const int ch1 = (wv * 2 + 1) * 512;

#define STAGE_B(kt, sl_)                                                      \
  do {                                                                        \
    const size_t ko = (size_t)(kt)*BK;                                        \
    __builtin_amdgcn_global_load_lds((const GLOBAL_AS void*)(gB0 + ko),       \
                                     (LDS_AS void*)(&sB[sl_][ch0]), 16, 0, 0);\
    __builtin_amdgcn_global_load_lds((const GLOBAL_AS void*)(gB1 + ko),       \
                                     (LDS_AS void*)(&sB[sl_][ch1]), 16, 0, 0);\
  } while (0)

  // ---- read addressing (16x16x32 frag: m = lane&15, k = (lane>>4)*8+j)
  const int rdrow = lane & 15;
  const int slot4 = (lane >> 4) ^ ((lane >> 1) & 3);           // swizzled slot
  const int aoff = (wm * 128 + rdrow) * BK + slot4 * 8;        // + mf*512
  const int boff = (wn * 64 + rdrow) * BK + slot4 * 8;         // + nf*512

  f32x4 acc[8][4];
#pragma unroll
  for (int mf = 0; mf < 8; ++mf)
#pragma unroll
    for (int nf = 0; nf < 4; ++nf) acc[mf][nf] = (f32x4){0.f, 0.f, 0.f, 0.f};

  // ---- prologue: A tiles 0..2 load-cvt-write; issue x(3) regs; B 0..2.
  float4 a00, a01, a10, a11;   // x regs for the next A tile (tile t+3)
#pragma unroll
  for (int p = 0; p < 3; ++p) {
    const size_t ko = (size_t)p * BK;
    float4 t00 = *(const float4*)(xr0 + ko);
    float4 t01 = *(const float4*)(xr0 + ko + 4);
    float4 t10 = *(const float4*)(xr1 + ko);
    float4 t11 = *(const float4*)(xr1 + ko + 4);
    *(int4*)&sA[p][ch0 + lane * 8] = cvt8(t00, t01);
    *(int4*)&sA[p][ch1 + lane * 8] = cvt8(t10, t11);
  }
  {
    const size_t ko = (size_t)3 * BK;
    a00 = *(const float4*)(xr0 + ko);
    a01 = *(const float4*)(xr0 + ko + 4);
    a10 = *(const float4*)(xr1 + ko);
    a11 = *(const float4*)(xr1 + ko + 4);
  }
  STAGE_B(0, 0);
  STAGE_B(1, 1);
  STAGE_B(2, 2);
  asm volatile("s_waitcnt vmcnt(4)" ::: "memory");   // B(0) (+x(3)) landed
  asm volatile("s_waitcnt lgkmcnt(0)" ::: "memory"); // A writes visible
  __builtin_amdgcn_s_barrier();
  asm volatile("" ::: "memory");

  for (int t = 0; t < NT; ++t) {
    const int sl = t & 3;
    const int slw = (t + 3) & 3;
    bf16x8 af[8], bfr[4];
#pragma unroll
    for (int nf = 0; nf < 4; ++nf)
      bfr[nf] = *(const bf16x8*)&sB[sl][boff + nf * 512];
#pragma unroll
    for (int mf = 0; mf < 8; ++mf)
      af[mf] = *(const bf16x8*)&sA[sl][aoff + mf * 512];

    if (t + 3 < NT) {
      // convert x regs (tile t+3, loaded last iter; compiler emits the
      // counted vmcnt wait here, which also retires B(t+1)) and write LDS.
      *(int4*)&sA[slw][ch0 + lane * 8] = cvt8(a00, a01);
      *(int4*)&sA[slw][ch1 + lane * 8] = cvt8(a10, a11);
    }
    if (t + 4 < NT) {   // issue x loads for tile t+4
      const size_t ko = (size_t)(t + 4) * BK;
      a00 = *(const float4*)(xr0 + ko);
      a01 = *(const float4*)(xr0 + ko + 4);
      a10 = *(const float4*)(xr1 + ko);
      a11 = *(const float4*)(xr1 + ko + 4);
    }
    if (t + 3 < NT) STAGE_B(t + 3, slw);

    // R3 schedule: drain LDS (frag reads + A writes), pin, tight MFMA cluster
    asm volatile("s_waitcnt lgkmcnt(0)" ::: "memory");
    __builtin_amdgcn_sched_barrier(0);
    __builtin_amdgcn_s_setprio(1);
#pragma unroll
    for (int mf = 0; mf < 8; ++mf)
#pragma unroll
      for (int nf = 0; nf < 4; ++nf)
        acc[mf][nf] = __builtin_amdgcn_mfma_f32_16x16x32_bf16(
            af[mf], bfr[nf], acc[mf][nf], 0, 0, 0);
    __builtin_amdgcn_s_setprio(0);

    // gate (T4, counted, never full-drain in steady state):
    // steady outstanding at gate = B(t+2)2 + x(t+4)4 + B(t+3)2 = 8.
    // tail: t+3==NT -> keep newest B tile (2); else drain.
    if (t < NT - 1) {
      if (t + 3 < NT) {
        asm volatile("s_waitcnt vmcnt(8)" ::: "memory");
      } else if (t + 3 == NT) {
        asm volatile("s_waitcnt vmcnt(2)" ::: "memory");
      } else {
        asm volatile("s_waitcnt vmcnt(0)" ::: "memory");
      }
      __builtin_amdgcn_s_barrier();
      asm volatile("" ::: "memory");
    }
  }
#undef STAGE_B

  // ---- epilogue: 16x16 C/D layout col = lane&15, row = (lane>>4)*4 + r
#pragma unroll
  for (int nf = 0; nf < 4; ++nf) {
    const int n = (int)n0 + wn * 64 + nf * 16 + (lane & 15);
    const float bv = bias[n];
#pragma unroll
    for (int mf = 0; mf < 8; ++mf) {
      const size_t mb = m0 + wm * 128 + mf * 16 + (lane >> 4) * 4;
#pragma unroll
      for (int r = 0; r < 4; ++r) {
        C[(mb + r) * N_DIM + n] = acc[mf][nf][r] + bv;
      }
    }
  }
}

// ---------------- fallback (only if ws too small) -------------------------
__global__ void fallback_kernel(const float* __restrict__ x,
                                const int* __restrict__ wq,
                                const float* __restrict__ wscale,
                                const float* __restrict__ bias,
                                float* __restrict__ out) {
  __shared__ float xs[K_DIM];
  const size_t m = blockIdx.x;
  for (int k = threadIdx.x; k < K_DIM; k += 256) xs[k] = x[m * K_DIM + k];
  __syncthreads();
  for (int n = threadIdx.x; n < N_DIM; n += 256) {
    const int* wr = wq + (size_t)n * K_DIM;
    float s = 0.f;
    for (int k = 0; k < K_DIM; ++k) s += xs[k] * (float)wr[k];
    out[m * N_DIM + n] = s * wscale[n] + bias[n];
  }
}

extern "C" void kernel_launch(void* const* d_in, const int* in_sizes, int n_in,
                              void* d_out, int out_size, void* d_ws, size_t ws_size,
                              hipStream_t stream) {
  const float* x       = (const float*)d_in[0];
  const int*   w_q     = (const int*)d_in[1];
  const float* w_scale = (const float*)d_in[2];
  const float* bias    = (const float*)d_in[3];
  const float* lora_A  = (const float*)d_in[4];
  const float* lora_S  = (const float*)d_in[5];
  const float* lora_B  = (const float*)d_in[6];
  float* out = (float*)d_out;

  const size_t need = (size_t)N_DIM * K_DIM * sizeof(unsigned short); // 32 MB
  if (ws_size < need) {
    fallback_kernel<<<M_DIM, 256, 0, stream>>>(x, w_q, w_scale, bias, out);
    return;
  }

  unsigned short* Wbf = (unsigned short*)d_ws;

  fold_kernel<<<(N_DIM / 4) * (K_DIM / 2048), 256, 0, stream>>>(
      w_q, w_scale, lora_A, lora_S, lora_B, Wbf);
  gemm_bias_kernel<<<dim3((N_DIM / BN) * (M_DIM / BM)), 512, 0, stream>>>(
      x, Wbf, bias, out);
}

// Round 5
// 533.317 us; speedup vs baseline: 1.1282x; 1.1282x over previous
//
#include <hip/hip_runtime.h>

// SVDQuantLinear: out[m,n] = x[m,:] . (w_q[n,:]*w_scale[n]) + bias[n] + lora
// Fold rank-32 LoRA into dequantized W (fp32, one bf16 round) -> one bf16 GEMM.
// R3: 256x256/BK=32 ring-4, counted vmcnt(8), lgkm(0)+sched_barrier+setprio
//     cluster, XCD swizzle -> conflicts 0, MfmaUtil 48%, gemm 258us. BEST.
// R4 FAILED: coarse 2-phase split -> 298us (extra barriers/drains).
// R5: fused prep GOOD (non-gemm 290->258.6us); gemm drain-removal BAD
//     (258->268.6us, compiler interleave < tight drained cluster).
// R6 FAILED: fp32-A reg-staging -> FETCH 584MB->1.08GB, gemm 366us; prep
//     saved only ~23us. Calibration: fixed overhead ~220us, cast ~25-30us,
//     fold ~10-15us.
// R7 (this round): recombine best-measured components, never yet benched
//     together: R3-exact GEMM (258us) + R5 fused prep (258.6us non-gemm).
//     Pure revert/anchor round; no new schedule variables.

#define M_DIM 8192   // B*S
#define N_DIM 4096   // D_OUT
#define K_DIM 4096   // D_IN
#define R_DIM 32

#define BM 256
#define BN 256
#define BK 32                 // 64 B per row in LDS
#define NT (K_DIM / BK)       // 128 k-tiles
#define NSLOT 4               // LDS ring: 4 * (16KB A + 16KB B) = 128 KiB

typedef short bf16x8 __attribute__((ext_vector_type(8)));
typedef float f32x4 __attribute__((ext_vector_type(4)));
typedef unsigned short u16x8 __attribute__((ext_vector_type(8)));

#define GLOBAL_AS __attribute__((address_space(1)))
#define LDS_AS __attribute__((address_space(3)))

__device__ __forceinline__ unsigned short f2bf(float f) {
  union { float f; unsigned u; } v;
  v.f = f;
  unsigned u = v.u;
  u += 0x7fffu + ((u >> 16) & 1u);  // RNE (finite inputs)
  return (unsigned short)(u >> 16);
}

// ---------------- fused prep: cast x -> bf16 AND fold W_eff -> bf16 --------
// blocks [0, 16384): cast 2048 x-elems each (float4 -> bf16x8).
// blocks [16384, 18432): fold 4 o-rows x 2048 i-cols of
//   W_eff = wq*scale + lora_B*diag(S)*lora_A.
#define CAST_BLOCKS 16384
__global__ void prep_kernel(const float* __restrict__ x,
                            const int* __restrict__ wq,
                            const float* __restrict__ wscale,
                            const float* __restrict__ lA,
                            const float* __restrict__ lS,
                            const float* __restrict__ lB,
                            unsigned short* __restrict__ Xbf,
                            unsigned short* __restrict__ Wbf) {
  __shared__ float bs[4][32];
  const int tid = threadIdx.x;

  if (blockIdx.x < CAST_BLOCKS) {
    size_t i = ((size_t)blockIdx.x * 256 + tid) * 8;
    float4 v0 = *(const float4*)(x + i);
    float4 v1 = *(const float4*)(x + i + 4);
    u16x8 o;
    o[0] = f2bf(v0.x); o[1] = f2bf(v0.y); o[2] = f2bf(v0.z); o[3] = f2bf(v0.w);
    o[4] = f2bf(v1.x); o[5] = f2bf(v1.y); o[6] = f2bf(v1.z); o[7] = f2bf(v1.w);
    *(u16x8*)(Xbf + i) = o;
    return;
  }

  const int bid2 = (int)blockIdx.x - CAST_BLOCKS;   // 0..2047
  const int o0 = (bid2 >> 1) * 4;                   // 1024 o-blocks x 4 rows
  const int i0 = (bid2 & 1) * 2048 + tid * 8;       // 2 i-blocks

  if (tid < 128) {
    int o = tid >> 5, r = tid & 31;
    bs[o][r] = lB[(size_t)(o0 + o) * R_DIM + r] * lS[r];
  }
  __syncthreads();

  float acc[4][8];
#pragma unroll
  for (int o = 0; o < 4; ++o)
#pragma unroll
    for (int j = 0; j < 8; ++j) acc[o][j] = 0.f;

  for (int r = 0; r < R_DIM; ++r) {
    float4 a0 = *(const float4*)(lA + (size_t)r * K_DIM + i0);
    float4 a1 = *(const float4*)(lA + (size_t)r * K_DIM + i0 + 4);
    float av[8] = {a0.x, a0.y, a0.z, a0.w, a1.x, a1.y, a1.z, a1.w};
#pragma unroll
    for (int o = 0; o < 4; ++o) {
      float b = bs[o][r];
#pragma unroll
      for (int j = 0; j < 8; ++j) acc[o][j] += b * av[j];
    }
  }

#pragma unroll
  for (int o = 0; o < 4; ++o) {
    float sc = wscale[o0 + o];
    const int* qp = wq + (size_t)(o0 + o) * K_DIM + i0;
    int4 q0 = *(const int4*)qp;
    int4 q1 = *(const int4*)(qp + 4);
    int qv[8] = {q0.x, q0.y, q0.z, q0.w, q1.x, q1.y, q1.z, q1.w};
    u16x8 ov;
#pragma unroll
    for (int j = 0; j < 8; ++j) ov[j] = f2bf(acc[o][j] + (float)qv[j] * sc);
    *(u16x8*)(Wbf + (size_t)(o0 + o) * K_DIM + i0) = ov;
  }
}

// ---------------- main GEMM: C = Xbf * Wbf^T + bias ------------------------
// R3-EXACT. 256x256 tile, BK=32, 512 thr = 8 waves (2M x 4N), wave = 128x64
// output = 8x4 frags of 16x16x32 MFMA. 4-slot LDS ring; stage t+3 while
// computing t; counted vmcnt(8) gate once per K-tile (2 k-tiles in flight
// across barriers). LDS: 16B line (row, sl) holds k-group g = sl^((row>>1)&3);
// staging keeps LDS dest linear, permutes per-lane GLOBAL k-offset (rule #21).
__global__ __launch_bounds__(512, 2) void gemm_bias_kernel(
    const unsigned short* __restrict__ A,   // [M, K] bf16 bits
    const unsigned short* __restrict__ B,   // [N, K] bf16 bits
    const float* __restrict__ bias,         // [N]
    float* __restrict__ C) {                // [M, N]
  __shared__ __align__(16) unsigned short sA[NSLOT][BM * BK];  // 4 x 16 KiB
  __shared__ __align__(16) unsigned short sB[NSLOT][BN * BK];  // 4 x 16 KiB

  const int tid = threadIdx.x;
  const int lane = tid & 63;
  const int wv = tid >> 6;      // 0..7
  const int wm = wv >> 2;       // 0..1
  const int wn = wv & 3;        // 0..3

  // T1: bijective XCD swizzle (grid = 512 = 8*64). XCD x owns 2 B-panels.
  const int bid = (int)blockIdx.x;
  const int s = ((bid & 7) << 6) + (bid >> 3);
  const int bn_ = s >> 5;       // 0..15
  const int bm_ = s & 31;       // 0..31
  const size_t m0 = (size_t)bm_ * BM;
  const size_t n0 = (size_t)bn_ * BN;

  // ---- staging: lane l -> local row l>>2, 16B slot l&3,
  // global k-group (l&3)^((l>>3)&3); LDS dest linear (wave-uniform base).
  const int lrow = lane >> 2;                                  // 0..15
  const int gsl = (((lane & 3) ^ ((lane >> 3) & 3))) * 8;      // k elems
  const int r0 = (wv * 2) * 16 + lrow;                         // chunk c=0 row
  const unsigned short* gA0 = A + (m0 + r0) * (size_t)K_DIM + gsl;
  const unsigned short* gA1 = gA0 + 16 * (size_t)K_DIM;
  const unsigned short* gB0 = B + (n0 + r0) * (size_t)K_DIM + gsl;
  const unsigned short* gB1 = gB0 + 16 * (size_t)K_DIM;
  const int ch0 = (wv * 2 + 0) * 512;   // LDS chunk bases (shorts, 1KB each)
  const int ch1 = (wv * 2 + 1) * 512;

#define STAGE_ALL(kt, sl_)                                                    \
  do {                                                                        \
    const size_t ko = (size_t)(kt)*BK;                                        \
    __builtin_amdgcn_global_load_lds((const GLOBAL_AS void*)(gA0 + ko),       \
                                     (LDS_AS void*)(&sA[sl_][ch0]), 16, 0, 0);\
    __builtin_amdgcn_global_load_lds((const GLOBAL_AS void*)(gA1 + ko),       \
                                     (LDS_AS void*)(&sA[sl_][ch1]), 16, 0, 0);\
    __builtin_amdgcn_global_load_lds((const GLOBAL_AS void*)(gB0 + ko),       \
                                     (LDS_AS void*)(&sB[sl_][ch0]), 16, 0, 0);\
    __builtin_amdgcn_global_load_lds((const GLOBAL_AS void*)(gB1 + ko),       \
                                     (LDS_AS void*)(&sB[sl_][ch1]), 16, 0, 0);\
  } while (0)

  // ---- read addressing (16x16x32 frag: m = lane&15, k = (lane>>4)*8+j)
  const int rdrow = lane & 15;
  const int slot4 = (lane >> 4) ^ ((lane >> 1) & 3);           // swizzled slot
  const int aoff = (wm * 128 + rdrow) * BK + slot4 * 8;        // + mf*512
  const int boff = (wn * 64 + rdrow) * BK + slot4 * 8;         // + nf*512

  f32x4 acc[8][4];
#pragma unroll
  for (int mf = 0; mf < 8; ++mf)
#pragma unroll
    for (int nf = 0; nf < 4; ++nf) acc[mf][nf] = (f32x4){0.f, 0.f, 0.f, 0.f};

  // ---- prologue: 3 k-tiles in flight; wait only for tile 0 (vmcnt(8)).
  STAGE_ALL(0, 0);
  STAGE_ALL(1, 1);
  STAGE_ALL(2, 2);
  asm volatile("s_waitcnt vmcnt(8)" ::: "memory");
  __builtin_amdgcn_s_barrier();
  asm volatile("" ::: "memory");

  for (int t = 0; t < NT; ++t) {
    const int sl = t & 3;
    bf16x8 af[8], bfr[4];
#pragma unroll
    for (int mf = 0; mf < 8; ++mf)
      af[mf] = *(const bf16x8*)&sA[sl][aoff + mf * 512];
#pragma unroll
    for (int nf = 0; nf < 4; ++nf)
      bfr[nf] = *(const bf16x8*)&sB[sl][boff + nf * 512];

    if (t + 3 < NT) STAGE_ALL(t + 3, (t + 3) & 3);  // overwrites slot (t-1)&3

    // reads must retire before this wave can cross the barrier (slot reuse);
    // rule #18: pin with sched_barrier so MFMAs can't hoist past the wait.
    asm volatile("s_waitcnt lgkmcnt(0)" ::: "memory");
    __builtin_amdgcn_sched_barrier(0);

    __builtin_amdgcn_s_setprio(1);
#pragma unroll
    for (int mf = 0; mf < 8; ++mf)
#pragma unroll
      for (int nf = 0; nf < 4; ++nf)
        acc[mf][nf] = __builtin_amdgcn_mfma_f32_16x16x32_bf16(
            af[mf], bfr[nf], acc[mf][nf], 0, 0, 0);
    __builtin_amdgcn_s_setprio(0);

    // gate: k-tile t+1 must be resident for the next iteration; keep the 2
    // newest k-tiles (8 loads) in flight across the barrier (T4, no drain).
    if (t < NT - 1) {
      if (t + 3 < NT) {
        asm volatile("s_waitcnt vmcnt(8)" ::: "memory");
      } else if (t + 3 == NT) {
        asm volatile("s_waitcnt vmcnt(4)" ::: "memory");
      } else {
        asm volatile("s_waitcnt vmcnt(0)" ::: "memory");
      }
      __builtin_amdgcn_s_barrier();
      asm volatile("" ::: "memory");
    }
  }
#undef STAGE_ALL

  // ---- epilogue: 16x16 C/D layout col = lane&15, row = (lane>>4)*4 + r
#pragma unroll
  for (int nf = 0; nf < 4; ++nf) {
    const int n = (int)n0 + wn * 64 + nf * 16 + (lane & 15);
    const float bv = bias[n];
#pragma unroll
    for (int mf = 0; mf < 8; ++mf) {
      const size_t mb = m0 + wm * 128 + mf * 16 + (lane >> 4) * 4;
#pragma unroll
      for (int r = 0; r < 4; ++r) {
        C[(mb + r) * N_DIM + n] = acc[mf][nf][r] + bv;
      }
    }
  }
}

// ---------------- fallback (only if ws too small) -------------------------
__global__ void fallback_kernel(const float* __restrict__ x,
                                const int* __restrict__ wq,
                                const float* __restrict__ wscale,
                                const float* __restrict__ bias,
                                float* __restrict__ out) {
  __shared__ float xs[K_DIM];
  const size_t m = blockIdx.x;
  for (int k = threadIdx.x; k < K_DIM; k += 256) xs[k] = x[m * K_DIM + k];
  __syncthreads();
  for (int n = threadIdx.x; n < N_DIM; n += 256) {
    const int* wr = wq + (size_t)n * K_DIM;
    float s = 0.f;
    for (int k = 0; k < K_DIM; ++k) s += xs[k] * (float)wr[k];
    out[m * N_DIM + n] = s * wscale[n] + bias[n];
  }
}

extern "C" void kernel_launch(void* const* d_in, const int* in_sizes, int n_in,
                              void* d_out, int out_size, void* d_ws, size_t ws_size,
                              hipStream_t stream) {
  const float* x       = (const float*)d_in[0];
  const int*   w_q     = (const int*)d_in[1];
  const float* w_scale = (const float*)d_in[2];
  const float* bias    = (const float*)d_in[3];
  const float* lora_A  = (const float*)d_in[4];
  const float* lora_S  = (const float*)d_in[5];
  const float* lora_B  = (const float*)d_in[6];
  float* out = (float*)d_out;

  const size_t need = ((size_t)M_DIM + N_DIM) * K_DIM * sizeof(unsigned short); // 96 MB
  if (ws_size < need) {
    fallback_kernel<<<M_DIM, 256, 0, stream>>>(x, w_q, w_scale, bias, out);
    return;
  }

  unsigned short* Xbf = (unsigned short*)d_ws;
  unsigned short* Wbf = Xbf + (size_t)M_DIM * K_DIM;

  prep_kernel<<<CAST_BLOCKS + (N_DIM / 4) * (K_DIM / 2048), 256, 0, stream>>>(
      x, w_q, w_scale, lora_A, lora_S, lora_B, Xbf, Wbf);
  gemm_bias_kernel<<<dim3((N_DIM / BN) * (M_DIM / BM)), 512, 0, stream>>>(
      Xbf, Wbf, bias, out);
}

// Round 6
// 532.796 us; speedup vs baseline: 1.1293x; 1.0010x over previous
//
#include <hip/hip_runtime.h>

// SVDQuantLinear: out[m,n] = x[m,:] . (w_q[n,:]*w_scale[n]) + bias[n] + lora
// Fold rank-32 LoRA into dequantized W (fp32, one bf16 round) -> one bf16 GEMM.
// R3: 256x256/BK=32 ring-4, counted vmcnt, drained+pinned MFMA cluster,
//     XCD swizzle -> conflicts 0, MfmaUtil 46-48%, gemm 258-273us.
// R4 FAILED: coarse 2-phase split (298us). R5 FAILED: drain removal (268us).
// R6 FAILED: fp32-A reg-staging (366us, FETCH 2x). R7: clean anchor 533us =
//     ~220 fixed + ~40 prep + ~273 gemm.
// R8 (this round): cross-K-tile REGISTER double-buffer of fragments.
//     Iter t: {read tile t+1 frags into spare reg set | stage tile t+4 into
//     slot t&3 | 32-MFMA cluster on tile t's ALREADY-LOADED regs (zero wait
//     in front) | lgkm(0) (t+1 reads, ~free) | vmcnt(4) (t+3, ~free) |
//     barrier}. Removes the per-tile serial {reads -> full drain -> MFMA}
//     chain (~50% of cycle budget was overlap loss). Hard liveness: slot t&3
//     last LDS-read was iter t-1 (1 barrier separation); staged tiles are
//     vmcnt-retired >=2 gates before first read. Loop unrolled x2 to
//     ping-pong reg sets with static indexing (rule #20).

#define M_DIM 8192   // B*S
#define N_DIM 4096   // D_OUT
#define K_DIM 4096   // D_IN
#define R_DIM 32

#define BM 256
#define BN 256
#define BK 32                 // 64 B per row in LDS
#define NT (K_DIM / BK)       // 128 k-tiles
#define NSLOT 4               // LDS ring: 4 * (16KB A + 16KB B) = 128 KiB

typedef short bf16x8 __attribute__((ext_vector_type(8)));
typedef float f32x4 __attribute__((ext_vector_type(4)));
typedef unsigned short u16x8 __attribute__((ext_vector_type(8)));

#define GLOBAL_AS __attribute__((address_space(1)))
#define LDS_AS __attribute__((address_space(3)))

__device__ __forceinline__ unsigned short f2bf(float f) {
  union { float f; unsigned u; } v;
  v.f = f;
  unsigned u = v.u;
  u += 0x7fffu + ((u >> 16) & 1u);  // RNE (finite inputs)
  return (unsigned short)(u >> 16);
}

// ---------------- fused prep: cast x -> bf16 AND fold W_eff -> bf16 --------
#define CAST_BLOCKS 16384
__global__ void prep_kernel(const float* __restrict__ x,
                            const int* __restrict__ wq,
                            const float* __restrict__ wscale,
                            const float* __restrict__ lA,
                            const float* __restrict__ lS,
                            const float* __restrict__ lB,
                            unsigned short* __restrict__ Xbf,
                            unsigned short* __restrict__ Wbf) {
  __shared__ float bs[4][32];
  const int tid = threadIdx.x;

  if (blockIdx.x < CAST_BLOCKS) {
    size_t i = ((size_t)blockIdx.x * 256 + tid) * 8;
    float4 v0 = *(const float4*)(x + i);
    float4 v1 = *(const float4*)(x + i + 4);
    u16x8 o;
    o[0] = f2bf(v0.x); o[1] = f2bf(v0.y); o[2] = f2bf(v0.z); o[3] = f2bf(v0.w);
    o[4] = f2bf(v1.x); o[5] = f2bf(v1.y); o[6] = f2bf(v1.z); o[7] = f2bf(v1.w);
    *(u16x8*)(Xbf + i) = o;
    return;
  }

  const int bid2 = (int)blockIdx.x - CAST_BLOCKS;   // 0..2047
  const int o0 = (bid2 >> 1) * 4;                   // 1024 o-blocks x 4 rows
  const int i0 = (bid2 & 1) * 2048 + tid * 8;       // 2 i-blocks

  if (tid < 128) {
    int o = tid >> 5, r = tid & 31;
    bs[o][r] = lB[(size_t)(o0 + o) * R_DIM + r] * lS[r];
  }
  __syncthreads();

  float acc[4][8];
#pragma unroll
  for (int o = 0; o < 4; ++o)
#pragma unroll
    for (int j = 0; j < 8; ++j) acc[o][j] = 0.f;

  for (int r = 0; r < R_DIM; ++r) {
    float4 a0 = *(const float4*)(lA + (size_t)r * K_DIM + i0);
    float4 a1 = *(const float4*)(lA + (size_t)r * K_DIM + i0 + 4);
    float av[8] = {a0.x, a0.y, a0.z, a0.w, a1.x, a1.y, a1.z, a1.w};
#pragma unroll
    for (int o = 0; o < 4; ++o) {
      float b = bs[o][r];
#pragma unroll
      for (int j = 0; j < 8; ++j) acc[o][j] += b * av[j];
    }
  }

#pragma unroll
  for (int o = 0; o < 4; ++o) {
    float sc = wscale[o0 + o];
    const int* qp = wq + (size_t)(o0 + o) * K_DIM + i0;
    int4 q0 = *(const int4*)qp;
    int4 q1 = *(const int4*)(qp + 4);
    int qv[8] = {q0.x, q0.y, q0.z, q0.w, q1.x, q1.y, q1.z, q1.w};
    u16x8 ov;
#pragma unroll
    for (int j = 0; j < 8; ++j) ov[j] = f2bf(acc[o][j] + (float)qv[j] * sc);
    *(u16x8*)(Wbf + (size_t)(o0 + o) * K_DIM + i0) = ov;
  }
}

// ---------------- main GEMM: C = Xbf * Wbf^T + bias ------------------------
// 256x256 tile, BK=32, 512 thr = 8 waves (2M x 4N), wave = 128x64 output =
// 8x4 frags of 16x16x32 MFMA. Ring-4 LDS; register-double-buffered frags.
// LDS: 16B line (row, sl) holds k-group g = sl^((row>>1)&3); staging keeps
// LDS dest linear, permutes per-lane GLOBAL k-offset (rule #21).
__global__ __launch_bounds__(512, 2) void gemm_bias_kernel(
    const unsigned short* __restrict__ A,   // [M, K] bf16 bits
    const unsigned short* __restrict__ B,   // [N, K] bf16 bits
    const float* __restrict__ bias,         // [N]
    float* __restrict__ C) {                // [M, N]
  __shared__ __align__(16) unsigned short sA[NSLOT][BM * BK];  // 4 x 16 KiB
  __shared__ __align__(16) unsigned short sB[NSLOT][BN * BK];  // 4 x 16 KiB

  const int tid = threadIdx.x;
  const int lane = tid & 63;
  const int wv = tid >> 6;      // 0..7
  const int wm = wv >> 2;       // 0..1
  const int wn = wv & 3;        // 0..3

  // T1: bijective XCD swizzle (grid = 512 = 8*64). XCD x owns 2 B-panels.
  const int bid = (int)blockIdx.x;
  const int s = ((bid & 7) << 6) + (bid >> 3);
  const int bn_ = s >> 5;       // 0..15
  const int bm_ = s & 31;       // 0..31
  const size_t m0 = (size_t)bm_ * BM;
  const size_t n0 = (size_t)bn_ * BN;

  // ---- staging: lane l -> local row l>>2, 16B slot l&3,
  // global k-group (l&3)^((l>>3)&3); LDS dest linear (wave-uniform base).
  const int lrow = lane >> 2;                                  // 0..15
  const int gsl = (((lane & 3) ^ ((lane >> 3) & 3))) * 8;      // k elems
  const int r0 = (wv * 2) * 16 + lrow;                         // chunk c=0 row
  const unsigned short* gA0 = A + (m0 + r0) * (size_t)K_DIM + gsl;
  const unsigned short* gA1 = gA0 + 16 * (size_t)K_DIM;
  const unsigned short* gB0 = B + (n0 + r0) * (size_t)K_DIM + gsl;
  const unsigned short* gB1 = gB0 + 16 * (size_t)K_DIM;
  const int ch0 = (wv * 2 + 0) * 512;   // LDS chunk bases (shorts, 1KB each)
  const int ch1 = (wv * 2 + 1) * 512;

#define STAGE_ALL(kt, sl_)                                                    \
  do {                                                                        \
    const size_t ko = (size_t)(kt)*BK;                                        \
    __builtin_amdgcn_global_load_lds((const GLOBAL_AS void*)(gA0 + ko),       \
                                     (LDS_AS void*)(&sA[sl_][ch0]), 16, 0, 0);\
    __builtin_amdgcn_global_load_lds((const GLOBAL_AS void*)(gA1 + ko),       \
                                     (LDS_AS void*)(&sA[sl_][ch1]), 16, 0, 0);\
    __builtin_amdgcn_global_load_lds((const GLOBAL_AS void*)(gB0 + ko),       \
                                     (LDS_AS void*)(&sB[sl_][ch0]), 16, 0, 0);\
    __builtin_amdgcn_global_load_lds((const GLOBAL_AS void*)(gB1 + ko),       \
                                     (LDS_AS void*)(&sB[sl_][ch1]), 16, 0, 0);\
  } while (0)

  // ---- read addressing (16x16x32 frag: m = lane&15, k = (lane>>4)*8+j)
  const int rdrow = lane & 15;
  const int slot4 = (lane >> 4) ^ ((lane >> 1) & 3);           // swizzled slot
  const int aoff = (wm * 128 + rdrow) * BK + slot4 * 8;        // + mf*512
  const int boff = (wn * 64 + rdrow) * BK + slot4 * 8;         // + nf*512

#define READ_FRAGS(AF, BF, sl_)                                               \
  do {                                                                        \
    _Pragma("unroll")                                                         \
    for (int nf = 0; nf < 4; ++nf)                                            \
      BF[nf] = *(const bf16x8*)&sB[sl_][boff + nf * 512];                     \
    _Pragma("unroll")                                                         \
    for (int mf = 0; mf < 8; ++mf)                                            \
      AF[mf] = *(const bf16x8*)&sA[sl_][aoff + mf * 512];                     \
  } while (0)

#define MFMA_CLUSTER(AF, BF)                                                  \
  do {                                                                        \
    __builtin_amdgcn_s_setprio(1);                                            \
    _Pragma("unroll")                                                         \
    for (int mf = 0; mf < 8; ++mf)                                            \
      _Pragma("unroll")                                                       \
      for (int nf = 0; nf < 4; ++nf)                                          \
        acc[mf][nf] = __builtin_amdgcn_mfma_f32_16x16x32_bf16(                \
            AF[mf], BF[nf], acc[mf][nf], 0, 0, 0);                            \
    __builtin_amdgcn_s_setprio(0);                                            \
  } while (0)

#define GATE(cnt4)                                                            \
  do {                                                                        \
    asm volatile("s_waitcnt lgkmcnt(0)" ::: "memory");                        \
    if (cnt4) { asm volatile("s_waitcnt vmcnt(4)" ::: "memory"); }            \
    else      { asm volatile("s_waitcnt vmcnt(0)" ::: "memory"); }            \
    __builtin_amdgcn_s_barrier();                                             \
    asm volatile("" ::: "memory");                                            \
  } while (0)

  f32x4 acc[8][4];
#pragma unroll
  for (int mf = 0; mf < 8; ++mf)
#pragma unroll
    for (int nf = 0; nf < 4; ++nf) acc[mf][nf] = (f32x4){0.f, 0.f, 0.f, 0.f};

  bf16x8 a0[8], b0[4], a1[8], b1[4];   // ping-pong fragment sets

  // ---- prologue: stage tiles 0-3; tiles 0,1 resident; read cur = tile 0.
  STAGE_ALL(0, 0);
  STAGE_ALL(1, 1);
  STAGE_ALL(2, 2);
  STAGE_ALL(3, 3);
  asm volatile("s_waitcnt vmcnt(8)" ::: "memory");
  __builtin_amdgcn_s_barrier();
  asm volatile("" ::: "memory");
  READ_FRAGS(a0, b0, 0);
  asm volatile("s_waitcnt lgkmcnt(0)" ::: "memory");
  __builtin_amdgcn_s_barrier();      // hard-separate cur-read from iter-0
  asm volatile("" ::: "memory");     // staging into slot 0

  for (int t = 0; t < NT; t += 2) {
    // ======== tile t: compute (a0,b0); prefetch tile t+1 -> (a1,b1) ========
    READ_FRAGS(a1, b1, (t + 1) & 3);
    if (t + 4 < NT) STAGE_ALL(t + 4, t & 3);
    __builtin_amdgcn_sched_barrier(0);
    MFMA_CLUSTER(a0, b0);
    GATE(t + 4 < NT);

    // ======== tile t+1: compute (a1,b1); prefetch tile t+2 -> (a0,b0) ======
    if (t + 2 < NT) READ_FRAGS(a0, b0, (t + 2) & 3);
    if (t + 5 < NT) STAGE_ALL(t + 5, (t + 1) & 3);
    __builtin_amdgcn_sched_barrier(0);
    MFMA_CLUSTER(a1, b1);
    if (t + 1 < NT - 1) GATE(t + 5 < NT);
  }
#undef STAGE_ALL
#undef READ_FRAGS
#undef MFMA_CLUSTER
#undef GATE

  // ---- epilogue: 16x16 C/D layout col = lane&15, row = (lane>>4)*4 + r
#pragma unroll
  for (int nf = 0; nf < 4; ++nf) {
    const int n = (int)n0 + wn * 64 + nf * 16 + (lane & 15);
    const float bv = bias[n];
#pragma unroll
    for (int mf = 0; mf < 8; ++mf) {
      const size_t mb = m0 + wm * 128 + mf * 16 + (lane >> 4) * 4;
#pragma unroll
      for (int r = 0; r < 4; ++r) {
        C[(mb + r) * N_DIM + n] = acc[mf][nf][r] + bv;
      }
    }
  }
}

// ---------------- fallback (only if ws too small) -------------------------
__global__ void fallback_kernel(const float* __restrict__ x,
                                const int* __restrict__ wq,
                                const float* __restrict__ wscale,
                                const float* __restrict__ bias,
                                float* __restrict__ out) {
  __shared__ float xs[K_DIM];
  const size_t m = blockIdx.x;
  for (int k = threadIdx.x; k < K_DIM; k += 256) xs[k] = x[m * K_DIM + k];
  __syncthreads();
  for (int n = threadIdx.x; n < N_DIM; n += 256) {
    const int* wr = wq + (size_t)n * K_DIM;
    float s = 0.f;
    for (int k = 0; k < K_DIM; ++k) s += xs[k] * (float)wr[k];
    out[m * N_DIM + n] = s * wscale[n] + bias[n];
  }
}

extern "C" void kernel_launch(void* const* d_in, const int* in_sizes, int n_in,
                              void* d_out, int out_size, void* d_ws, size_t ws_size,
                              hipStream_t stream) {
  const float* x       = (const float*)d_in[0];
  const int*   w_q     = (const int*)d_in[1];
  const float* w_scale = (const float*)d_in[2];
  const float* bias    = (const float*)d_in[3];
  const float* lora_A  = (const float*)d_in[4];
  const float* lora_S  = (const float*)d_in[5];
  const float* lora_B  = (const float*)d_in[6];
  float* out = (float*)d_out;

  const size_t need = ((size_t)M_DIM + N_DIM) * K_DIM * sizeof(unsigned short); // 96 MB
  if (ws_size < need) {
    fallback_kernel<<<M_DIM, 256, 0, stream>>>(x, w_q, w_scale, bias, out);
    return;
  }

  unsigned short* Xbf = (unsigned short*)d_ws;
  unsigned short* Wbf = Xbf + (size_t)M_DIM * K_DIM;

  prep_kernel<<<CAST_BLOCKS + (N_DIM / 4) * (K_DIM / 2048), 256, 0, stream>>>(
      x, w_q, w_scale, lora_A, lora_S, lora_B, Xbf, Wbf);
  gemm_bias_kernel<<<dim3((N_DIM / BN) * (M_DIM / BM)), 512, 0, stream>>>(
      Xbf, Wbf, bias, out);
}